// Round 13
// baseline (128.151 us; speedup 1.0000x reference)
//
#include <hip/hip_runtime.h>
#include <cstdint>
#include <cstddef>

// ---------------- problem constants ----------------
#define NIMG   8
#define NPROP  2000
#define NCLS   91
#define NFG    90
#define NROW   (NIMG * NPROP)      // 16000
#define TOPK   2048
#define DETS   100
#define CKCAP  32768
#define KREGS  8                   // register-resident keys/thread (8*1024=8192; cnt~6K)
#define CLSCAP 512                 // max candidates per (image,class) handled by kN

#define IMG_Wf 1333.0f
#define IMG_Hf 800.0f
#define SCORE_TH 0.05f
#define MINSZ    0.01f
#define NMS_TH   0.5f
#define CLIPV    4.135166556742356f   // log(1000/16) rounded to f32
#define ORD_NEG1 0x407FFFFFu          // ford(-1.0f)
#define PADKEY   (((ull)ORD_NEG1 << 32) | 0xFFFFFFFFull)

typedef unsigned long long ull;

// ---------------- workspace layout (bytes) ----------------
// zeroed region [0, 2048): cntv (8 counters, 256B apart)
static const size_t OFF_CNT    = 0;                                  // 2048
static const size_t OFF_VBM    = 4096;                               // 16000*2*8
static const size_t OFF_CK     = 262144;                             // 8*32768*8
static const size_t OFF_CBOX   = OFF_CK    + (size_t)NIMG*CKCAP*8;   // 8*2048*16
static const size_t OFF_CSCOR  = OFF_CBOX  + (size_t)NIMG*TOPK*16;   // 8*2048*4
static const size_t OFF_CLAB   = OFF_CSCOR + (size_t)NIMG*TOPK*4;    // 8*2048*4
static const size_t OFF_CLSBOX = OFF_CLAB  + (size_t)NIMG*TOPK*4;    // 8*2048*16
static const size_t OFF_CLSAR  = OFF_CLSBOX+ (size_t)NIMG*TOPK*16;   // 8*2048*4
static const size_t OFF_CLSKEY = OFF_CLSAR + (size_t)NIMG*TOPK*4;    // 8*2048*8
static const size_t OFF_KEEPF  = OFF_CLSKEY+ (size_t)NIMG*TOPK*8;    // 8*2048*4
static const size_t OFF_CLSCNT = OFF_KEEPF + (size_t)NIMG*TOPK*4;    // 8*96*4
static const size_t OFF_CLSOFF = OFF_CLSCNT+ (size_t)NIMG*96*4;      // 8*96*4

// ---------------- helpers ----------------
__device__ __forceinline__ unsigned ford(float f) {
    unsigned u = __float_as_uint(f);
    return (u & 0x80000000u) ? ~u : (u | 0x80000000u);
}
__device__ __forceinline__ float fordinv(unsigned x) {
    return (x & 0x80000000u) ? __uint_as_float(x & 0x7FFFFFFFu)
                             : __uint_as_float(~x);
}

// exact op-for-op mirror of reference _decode + clip (no FMA contraction)
__device__ __forceinline__ float4 decode_clip(float4 p, float4 r) {
    float w  = __fsub_rn(p.z, p.x);
    float h  = __fsub_rn(p.w, p.y);
    float cx = __fadd_rn(p.x, __fmul_rn(0.5f, w));
    float cy = __fadd_rn(p.y, __fmul_rn(0.5f, h));
    float dx = __fdiv_rn(r.x, 10.0f);
    float dy = __fdiv_rn(r.y, 10.0f);
    float dw = fminf(__fdiv_rn(r.z, 5.0f), CLIPV);
    float dh = fminf(__fdiv_rn(r.w, 5.0f), CLIPV);
    float pcx = __fadd_rn(__fmul_rn(dx, w), cx);
    float pcy = __fadd_rn(__fmul_rn(dy, h), cy);
    float pw  = __fmul_rn(expf(dw), w);
    float ph  = __fmul_rn(expf(dh), h);
    float x1 = __fsub_rn(pcx, __fmul_rn(0.5f, pw));
    float y1 = __fsub_rn(pcy, __fmul_rn(0.5f, ph));
    float x2 = __fadd_rn(pcx, __fmul_rn(0.5f, pw));
    float y2 = __fadd_rn(pcy, __fmul_rn(0.5f, ph));
    float4 o;
    o.x = fminf(fmaxf(x1, 0.0f), IMG_Wf);
    o.y = fminf(fmaxf(y1, 0.0f), IMG_Hf);
    o.z = fminf(fmaxf(x2, 0.0f), IMG_Wf);
    o.w = fminf(fmaxf(y2, 0.0f), IMG_Hf);
    return o;
}

// bitonic wave-local phase with payload: thread owns elements (base, base+1)
__device__ __forceinline__ void wl_pair(ull& a, ull& b, int& pa, int& pb,
                                        int l, int base, int k, int jmax) {
    bool desc = ((base & k) == 0);
    for (int j = jmax; j >= 2; j >>= 1) {
        int pl = l ^ (j >> 1);
        bool lower = ((base & j) == 0);
        ull qa = __shfl(a, pl), qb = __shfl(b, pl);
        int ra = __shfl(pa, pl), rb = __shfl(pb, pl);
        bool km = (desc == lower);
        bool ta = km ? (a > qa) : (a < qa);
        a = ta ? a : qa;  pa = ta ? pa : ra;
        bool tb = km ? (b > qb) : (b < qb);
        b = tb ? b : qb;  pb = tb ? pb : rb;
    }
    bool sw = ((a < b) == desc);
    if (sw) { ull t = a; a = b; b = t; int tp = pa; pa = pb; pb = tp; }
}

// ============ kernel A: softmax + decode + valid -> compacted keys + row bitmap ============
__global__ __launch_bounds__(1024) void kA(const float* __restrict__ logits,
                                           const float* __restrict__ reg,
                                           const float* __restrict__ props,
                                           ull* __restrict__ ck,
                                           int* __restrict__ cntv,
                                           ull* __restrict__ vbm2) {
    int warp = threadIdx.x >> 6;
    int lane = threadIdx.x & 63;
    int row  = blockIdx.x * 16 + warp;
    int b = row / NPROP;                 // uniform within block
    int n = row - b * NPROP;
    const float* lrow = logits + (size_t)row * NCLS;

    float xa = lrow[lane];
    float xb = (lane < 27) ? lrow[64 + lane] : -INFINITY;
    float mx = fmaxf(xa, xb);
    #pragma unroll
    for (int o = 32; o; o >>= 1) mx = fmaxf(mx, __shfl_xor(mx, o));
    float ea = expf(__fsub_rn(xa, mx));
    float eb = (lane < 27) ? expf(__fsub_rn(xb, mx)) : 0.0f;
    float s  = __fadd_rn(ea, eb);
    #pragma unroll
    for (int o = 32; o; o >>= 1) s = __fadd_rn(s, __shfl_xor(s, o));

    const float4 p = *reinterpret_cast<const float4*>(props + (size_t)row * 4);

    __shared__ int sCnt[32];
    __shared__ int sExc[32];
    __shared__ int sBase;

    ull rowmask[2];
    bool validA[2];
    ull keyA[2];
    #pragma unroll
    for (int it = 0; it < 2; ++it) {
        int c = (it == 0) ? (1 + lane) : (65 + lane);
        bool active = (it == 0) ? true : (lane < 26);
        bool valid = false;
        ull key = 0;
        if (active) {
            float lg = lrow[c];
            float score = __fdiv_rn(expf(__fsub_rn(lg, mx)), s);
            float4 r4 = *reinterpret_cast<const float4*>(
                reg + ((size_t)row * NCLS + c) * 4);
            float4 bx = decode_clip(p, r4);
            float bw = __fsub_rn(bx.z, bx.x);
            float bh = __fsub_rn(bx.w, bx.y);
            valid = (score > SCORE_TH) && (bw >= MINSZ) && (bh >= MINSZ);
            int offidx = n * NFG + (c - 1);
            key = ((ull)ford(score) << 32) |
                  (ull)(0xFFFFFFFFu - (unsigned)offidx);
        }
        ull bal = __ballot(valid);
        rowmask[it] = bal;
        validA[it] = valid;
        keyA[it] = key;
        if (lane == 0) sCnt[warp * 2 + it] = __popcll(bal);
    }
    __syncthreads();
    if (warp == 0) {
        int c = (lane < 32) ? sCnt[lane] : 0;
        int p2 = c;
        #pragma unroll
        for (int o = 1; o < 32; o <<= 1) {
            int v = __shfl_up(p2, o);
            if (lane >= o) p2 += v;
        }
        if (lane == 31) sBase = atomicAdd(&cntv[b * 64], p2);
        if (lane < 32) sExc[lane] = p2 - c;
    }
    __syncthreads();
    int base = sBase;
    #pragma unroll
    for (int it = 0; it < 2; ++it) {
        if (validA[it]) {
            int slot = base + sExc[warp * 2 + it] +
                       __popcll(rowmask[it] & ((1ull << lane) - 1ull));
            if (slot < CKCAP)
                ck[(size_t)b * CKCAP + slot] = keyA[it];
        }
    }
    if (lane == 0) {
        vbm2[(size_t)row * 2]     = rowmask[0];
        vbm2[(size_t)row * 2 + 1] = rowmask[1];
    }
}

// ============ kernel B: exact top-2048 select + decode + unsorted class bucketing ============
__global__ __launch_bounds__(1024) void kB(const ull* __restrict__ ck,
                                           const int* __restrict__ cntv,
                                           const ull* __restrict__ vbm2,
                                           const float* __restrict__ reg,
                                           const float* __restrict__ props,
                                           float4* __restrict__ cbox,
                                           float* __restrict__ cscore,
                                           int* __restrict__ clabel,
                                           float4* __restrict__ clsbox,
                                           float* __restrict__ clsarea,
                                           ull* __restrict__ clskey,
                                           int* __restrict__ keepflag,
                                           int* __restrict__ clscnt,
                                           int* __restrict__ clsoff) {
    int b = blockIdx.x;
    int tid = threadIdx.x;
    int lane = tid & 63, warp = tid >> 6;
    __shared__ ull sk[TOPK];
    __shared__ unsigned histw[16 * 256];    // per-wave histograms (16 KB)
    __shared__ unsigned wtot4[4];
    __shared__ ull sP;
    __shared__ int sRem, sCnt, sDone, sInv, sVT;
    __shared__ float sMax[16];
    __shared__ float sM1;
    __shared__ int rex[NPROP];
    __shared__ int wsum[16];
    __shared__ int ccnt[96], cplc[96], coff[96];

    int cnt = cntv[b * 64];
    if (cnt > CKCAP) cnt = CKCAP;
    const ull* K = ck + (size_t)b * CKCAP;

    if (cnt >= TOPK) {
        // ---- load keys into registers (coalesced, once) ----
        ull kreg[KREGS];
        #pragma unroll
        for (int r = 0; r < KREGS; ++r) {
            int i = tid + (r << 10);
            kreg[r] = (i < cnt) ? K[i] : 0ull;
        }
        // ---- 8x8-bit radix select with short-circuit (keys distinct:
        //      terminates after the 4 score-byte passes in practice) ----
        ull P = 0; int rem = TOPK;
        for (int pass = 7; pass >= 0; --pass) {
            int sh = pass * 8;
            *reinterpret_cast<uint4*>(&histw[tid * 4]) = make_uint4(0, 0, 0, 0);
            __syncthreads();
            ull pmask = (pass == 7) ? 0ull : (~0ull << (sh + 8));
            unsigned* hw = &histw[warp << 8];
            #pragma unroll
            for (int r = 0; r < KREGS; ++r) {
                int i = tid + (r << 10);
                if (i < cnt && (kreg[r] & pmask) == P)
                    atomicAdd(&hw[(unsigned)(kreg[r] >> sh) & 255u], 1u);
            }
            for (int i = (KREGS << 10) + tid; i < cnt; i += 1024) {   // rare tail
                ull k2 = K[i];
                if ((k2 & pmask) == P)
                    atomicAdd(&hw[(unsigned)(k2 >> sh) & 255u], 1u);
            }
            __syncthreads();
            unsigned x = 0, pfx = 0;
            if (tid < 256) {
                int d = 255 - tid;
                #pragma unroll
                for (int w = 0; w < 16; ++w) x += histw[(w << 8) + d];
                pfx = x;
                #pragma unroll
                for (int o = 1; o < 64; o <<= 1) {
                    unsigned v = __shfl_up(pfx, o);
                    if (lane >= o) pfx += v;
                }
                if (lane == 63) wtot4[tid >> 6] = pfx;
            }
            __syncthreads();
            if (tid < 256) {
                int d = 255 - tid;
                int ws = tid >> 6;
                unsigned add = 0;
                if (ws > 0) add += wtot4[0];
                if (ws > 1) add += wtot4[1];
                if (ws > 2) add += wtot4[2];
                unsigned pi   = pfx + add;    // suffixIncl(d)
                unsigned excl = pi - x;       // suffixExcl(d)
                if (x && excl < (unsigned)rem && pi >= (unsigned)rem) {
                    sP = P | ((ull)(unsigned)d << sh);
                    int nr = rem - (int)excl;
                    sRem = nr;
                    sDone = ((int)x == nr) ? 1 : 0;   // whole bin selected -> exact
                }
            }
            __syncthreads();
            P = sP; rem = sRem;
            if (sDone) break;      // threshold exact with remaining low bits zero
        }
        if (tid == 0) sCnt = 0;
        __syncthreads();
        // ---- wave-aggregated compaction from registers (unsorted) ----
        #pragma unroll
        for (int r = 0; r < KREGS; ++r) {
            int i = tid + (r << 10);
            bool sel = (i < cnt) && (kreg[r] >= P);
            ull bal = __ballot(sel);
            int cw = __popcll(bal);
            if (cw) {
                int ldr = __ffsll((long long)bal) - 1;
                int bw = 0;
                if (lane == ldr) bw = atomicAdd(&sCnt, cw);
                bw = __shfl(bw, ldr);
                if (sel) {
                    int pos = bw + __popcll(bal & ((1ull << lane) - 1ull));
                    if (pos < TOPK) sk[pos] = kreg[r];
                }
            }
        }
        for (int i = (KREGS << 10) + tid; i < cnt; i += 1024) {       // rare tail
            ull k2 = K[i];
            bool sel = (k2 >= P);
            ull bal = __ballot(sel);
            int cw = __popcll(bal);
            if (cw) {
                int ldr = __ffsll((long long)bal) - 1;
                int bw = 0;
                if (lane == ldr) bw = atomicAdd(&sCnt, cw);
                bw = __shfl(bw, ldr);
                if (sel) {
                    int pos = bw + __popcll(bal & ((1ull << lane) - 1ull));
                    if (pos < TOPK) sk[pos] = k2;
                }
            }
        }
        __syncthreads();
        int fc = sCnt;
        for (int i = fc + tid; i < TOPK; i += 1024) sk[i] = PADKEY;
    } else {
        // take all valid + fill with smallest-index invalid (score -1, ascending idx)
        for (int i = tid; i < cnt; i += 1024) sk[i] = K[i];
        int F = TOPK - cnt;
        const ull* V = vbm2 + (size_t)b * NPROP * 2;
        int r0 = 2 * tid, r1 = r0 + 1;
        int v0 = 0, v1 = 0;
        if (r0 < NPROP) v0 = NFG - __popcll(V[r0 * 2]) - __popcll(V[r0 * 2 + 1]);
        if (r1 < NPROP) v1 = NFG - __popcll(V[r1 * 2]) - __popcll(V[r1 * 2 + 1]);
        int s2 = v0 + v1;
        int pfx = s2;
        #pragma unroll
        for (int o = 1; o < 64; o <<= 1) {
            int t = __shfl_up(pfx, o);
            if (lane >= o) pfx += t;
        }
        if (lane == 63) wsum[warp] = pfx;
        __syncthreads();
        if (tid == 0) {
            int a = 0;
            for (int w = 0; w < 16; ++w) { int t = wsum[w]; wsum[w] = a; a += t; }
        }
        __syncthreads();
        int excl = pfx - s2 + wsum[warp];
        if (r0 < NPROP) rex[r0] = excl;
        if (r1 < NPROP) rex[r1] = excl + v0;
        __syncthreads();
        for (int r = tid; r < NPROP; r += 1024) {
            int e = rex[r];
            if (e < F) {
                ull m0 = V[r * 2], m1 = V[r * 2 + 1];
                int rank = e;
                ull inv = ~m0;
                while (inv && rank < F) {
                    int cb = __builtin_ctzll(inv); inv &= inv - 1;
                    unsigned idx = (unsigned)(r * NFG + cb);
                    sk[cnt + rank] = ((ull)ORD_NEG1 << 32) | (ull)(0xFFFFFFFFu - idx);
                    ++rank;
                }
                inv = (~m1) & ((1ull << 26) - 1ull);
                while (inv && rank < F) {
                    int cb = __builtin_ctzll(inv); inv &= inv - 1;
                    unsigned idx = (unsigned)(r * NFG + 64 + cb);
                    sk[cnt + rank] = ((ull)ORD_NEG1 << 32) | (ull)(0xFFFFFFFFu - idx);
                    ++rank;
                }
            }
        }
    }
    __syncthreads();

    // ---- decode the 2048 selected candidates (unsorted storage order) ----
    float lmax = 0.0f;
    float4 myb[2]; int myl[2]; float mys[2]; bool vkA[2]; ull kkA[2];
    #pragma unroll
    for (int r = 0; r < 2; ++r) {
        int pos0 = tid + r * 1024;
        ull k = sk[pos0];
        unsigned idx = 0xFFFFFFFFu - (unsigned)(k & 0xFFFFFFFFu);
        float score = fordinv((unsigned)(k >> 32));
        int n = (int)(idx / NFG), c = (int)(idx % NFG);     // label = c+1
        int row = b * NPROP + n;
        float4 p  = *reinterpret_cast<const float4*>(props + (size_t)row * 4);
        float4 r4 = *reinterpret_cast<const float4*>(
            reg + ((size_t)row * NCLS + (c + 1)) * 4);
        float4 bx = decode_clip(p, r4);
        myb[r] = bx; myl[r] = c + 1; mys[r] = score; kkA[r] = k;
        vkA[r] = (((unsigned)(k >> 32)) != ORD_NEG1);
        lmax = fmaxf(lmax, fmaxf(fmaxf(bx.x, bx.y), fmaxf(bx.z, bx.w)));
    }
    #pragma unroll
    for (int o = 32; o; o >>= 1) lmax = fmaxf(lmax, __shfl_xor(lmax, o));
    if ((tid & 63) == 0) sMax[tid >> 6] = lmax;
    if (tid < 96) { ccnt[tid] = 0; cplc[tid] = 0; }
    if (tid == 0) sInv = 0;
    __syncthreads();
    if (tid == 0) {
        float v = sMax[0];
        for (int i = 1; i < 16; ++i) v = fmaxf(v, sMax[i]);
        sM1 = __fadd_rn(v, 1.0f);            // jnp.max(cand_boxes) + 1.0
    }
    // phase 1: class counts
    #pragma unroll
    for (int r = 0; r < 2; ++r)
        if (vkA[r]) atomicAdd(&ccnt[myl[r] - 1], 1);
    __syncthreads();
    // wave-parallel exclusive prefix over the 90 class counts (warp 0)
    if (warp == 0) {
        int v0 = (lane < NFG) ? ccnt[lane] : 0;             // classes 0..63
        int p0 = v0;
        #pragma unroll
        for (int o = 1; o < 64; o <<= 1) {
            int t = __shfl_up(p0, o);
            if (lane >= o) p0 += t;
        }
        int v1 = (lane < NFG - 64) ? ccnt[64 + lane] : 0;   // classes 64..89
        int p1 = v1;
        #pragma unroll
        for (int o = 1; o < 64; o <<= 1) {
            int t = __shfl_up(p1, o);
            if (lane >= o) p1 += t;
        }
        int t0  = __shfl(p0, 63);
        int tot = t0 + __shfl(p1, NFG - 64 - 1);
        if (lane < NFG) coff[lane] = p0 - v0;
        if (lane < NFG - 64) coff[64 + lane] = t0 + p1 - v1;
        if (lane == 0) sVT = tot;
    }
    __syncthreads();
    float m1 = sM1;
    int validTot = sVT;
    // phase 2: placement (order within class arbitrary; kN sorts by key)
    #pragma unroll
    for (int r = 0; r < 2; ++r) {
        int slot;
        if (vkA[r]) {
            int cl = myl[r] - 1;
            slot = coff[cl] + atomicAdd(&cplc[cl], 1);
        } else {
            slot = validTot + atomicAdd(&sInv, 1);
        }
        int g2 = b * TOPK + slot;
        float off = __fmul_rn((float)myl[r], m1);
        float4 ob;
        ob.x = __fadd_rn(myb[r].x, off);
        ob.y = __fadd_rn(myb[r].y, off);
        ob.z = __fadd_rn(myb[r].z, off);
        ob.w = __fadd_rn(myb[r].w, off);
        float area = __fmul_rn(__fsub_rn(ob.z, ob.x), __fsub_rn(ob.w, ob.y));
        clsbox[g2] = ob; clsarea[g2] = area; clskey[g2] = kkA[r];
        cbox[g2] = myb[r]; cscore[g2] = mys[r]; clabel[g2] = myl[r];
        keepflag[g2] = 0;        // kN overwrites valid slots; invalid stay 0
    }
    if (tid < NFG) {
        clscnt[b * 96 + tid] = ccnt[tid];
        clsoff[b * 96 + tid] = coff[tid];
    }
}

// ============ kernel N: per-(image,class) key-sort + greedy NMS -> keepflag ============
__global__ __launch_bounds__(64) void kN(const float4* __restrict__ clsbox,
                                         const float* __restrict__ clsarea,
                                         const ull* __restrict__ clskey,
                                         const int* __restrict__ clscnt,
                                         const int* __restrict__ clsoff,
                                         int* __restrict__ keepflag) {
    int bc = blockIdx.x;
    int b = bc / NFG, c = bc - b * NFG;
    int n = clscnt[b * 96 + c];
    if (n <= 0) return;
    if (n > CLSCAP) n = CLSCAP;   // unreachable at observed densities
    int lane = threadIdx.x;
    int base = b * TOPK + clsoff[b * 96 + c];

    if (n <= 64) {
        // sort (key desc, payload slot) via shfl bitonic, pads sink (keys tiny)
        ull key = (lane < n) ? clskey[base + lane] : (ull)lane;
        int slot = (lane < n) ? (base + lane) : -1;
        #pragma unroll
        for (int k = 2; k <= 64; k <<= 1) {
            #pragma unroll
            for (int j = k >> 1; j > 0; j >>= 1) {
                int pl = lane ^ j;
                ull qk = __shfl(key, pl);
                int qs = __shfl(slot, pl);
                bool desc = ((lane & k) == 0);
                bool lower = ((lane & j) == 0);
                bool km = (desc == lower);
                bool keepown = km ? (key > qk) : (key < qk);
                key = keepown ? key : qk;
                slot = keepown ? slot : qs;
            }
        }
        float4 b0; float a0 = 0.0f;
        if (slot >= 0) { b0 = clsbox[slot]; a0 = clsarea[slot]; }
        ull alive = (n == 64) ? ~0ull : ((1ull << n) - 1ull);
        #pragma unroll 1
        for (int i = 0; i < n; ++i) {
            if (!((alive >> i) & 1ull)) continue;
            float bix = __shfl(b0.x, i), biy = __shfl(b0.y, i);
            float biz = __shfl(b0.z, i), biw = __shfl(b0.w, i);
            float ai2 = __shfl(a0, i);
            bool sup = false;
            if (lane < n && lane > i) {
                float lt0 = fmaxf(bix, b0.x), lt1 = fmaxf(biy, b0.y);
                float rb0 = fminf(biz, b0.z), rb1 = fminf(biw, b0.w);
                float w0 = fmaxf(__fsub_rn(rb0, lt0), 0.0f);
                float w1 = fmaxf(__fsub_rn(rb1, lt1), 0.0f);
                float inter = __fmul_rn(w0, w1);
                if (inter > 0.0f) {
                    float un = __fsub_rn(__fadd_rn(ai2, a0), inter);
                    sup = (__fdiv_rn(inter, un) > NMS_TH);
                }
            }
            alive &= ~__ballot(sup);
        }
        if (lane < n) keepflag[slot] = (int)((alive >> lane) & 1ull);
        return;
    }

    // ---- cold path: 64 < n <= 512 (statistically unreachable) ----
    __shared__ ull  skey[CLSCAP];
    __shared__ int  sslot[CLSCAP];
    __shared__ float4 sbox[CLSCAP];
    __shared__ float  sar[CLSCAP];
    __shared__ ull    smask[CLSCAP * 8];
    __shared__ ull    salive[8];
    for (int t = lane; t < n; t += 64) {
        skey[t] = clskey[base + t];
        sslot[t] = base + t;
    }
    __syncthreads();
    // selection sort descending (wave-parallel argmax per step)
    for (int r = 0; r < n - 1; ++r) {
        ull best = 0; int bi = -1;
        for (int t = r + lane; t < n; t += 64)
            if (skey[t] > best) { best = skey[t]; bi = t; }
        #pragma unroll
        for (int o = 32; o; o >>= 1) {
            ull ob = __shfl_xor(best, o);
            int oi = __shfl_xor(bi, o);
            if (ob > best) { best = ob; bi = oi; }
        }
        if (lane == 0 && bi != r) {
            ull tk = skey[r]; skey[r] = skey[bi]; skey[bi] = tk;
            int ts = sslot[r]; sslot[r] = sslot[bi]; sslot[bi] = ts;
        }
        __syncthreads();
    }
    for (int t = lane; t < n; t += 64) {
        sbox[t] = clsbox[sslot[t]];
        sar[t]  = clsarea[sslot[t]];
    }
    __syncthreads();
    int W = (n + 63) >> 6;
    for (int i = lane; i < n; i += 64) {
        float4 a = sbox[i]; float ai = sar[i];
        for (int w = 0; w < W; ++w) {
            ull word = 0;
            int jn = n - (w << 6); if (jn > 64) jn = 64;
            for (int s = 0; s < jn; ++s) {
                int j = (w << 6) + s;
                if (j > i) {
                    float4 cc = sbox[j];
                    float lt0 = fmaxf(a.x, cc.x), lt1 = fmaxf(a.y, cc.y);
                    float rb0 = fminf(a.z, cc.z), rb1 = fminf(a.w, cc.w);
                    float w0 = fmaxf(__fsub_rn(rb0, lt0), 0.0f);
                    float w1 = fmaxf(__fsub_rn(rb1, lt1), 0.0f);
                    float inter = __fmul_rn(w0, w1);
                    if (inter > 0.0f) {
                        float un = __fsub_rn(__fadd_rn(ai, sar[j]), inter);
                        if (__fdiv_rn(inter, un) > NMS_TH) word |= (1ull << s);
                    }
                }
            }
            smask[i * W + w] = word;
        }
    }
    __syncthreads();
    ull alive = 0;
    if (lane < W) {
        int rem = n - (lane << 6);
        alive = (rem >= 64) ? ~0ull : ((1ull << rem) - 1ull);
    }
    for (int i = 0; i < n; ++i) {
        ull aw = __shfl(alive, i >> 6);
        if ((aw >> (i & 63)) & 1ull) {
            if (lane < W) alive &= ~smask[i * W + lane];
        }
    }
    if (lane < W) salive[lane] = alive;
    __syncthreads();
    for (int t = lane; t < n; t += 64)
        keepflag[sslot[t]] = (int)((salive[t >> 6] >> (t & 63)) & 1ull);
}

// ============ kernel E: two-segment top-100 selection + emit ============
__global__ __launch_bounds__(1024) void kE(const int* __restrict__ keepflag,
                                           const ull* __restrict__ clskey,
                                           const float4* __restrict__ cbox,
                                           const float* __restrict__ cscore,
                                           const int* __restrict__ clabel,
                                           float* __restrict__ out) {
    int b = blockIdx.x;
    int tid = threadIdx.x;
    int lane = tid & 63, warp = tid >> 6;
    __shared__ ull kk[TOPK];
    __shared__ int ks[TOPK];
    __shared__ unsigned histw[16 * 256];
    __shared__ unsigned wtot4[4];
    __shared__ ull sP;
    __shared__ int sRem, sDone, sK, sFC;
    __shared__ ull fkey[128];
    __shared__ int fslot[128];

    const ull* KY = clskey + (size_t)b * TOPK;
    const int* KF = keepflag + (size_t)b * TOPK;

    int emitted = 0;
    #pragma unroll 1
    for (int seg = 0; seg < 2; ++seg) {
        __syncthreads();
        if (tid == 0) sK = 0;
        __syncthreads();
        if (emitted < DETS) {
            for (int s = tid; s < TOPK; s += 1024) {
                bool f = (seg == 0) ? (KF[s] != 0) : (KF[s] == 0);
                ull key = KY[s];
                ull bal = __ballot(f);
                int cw = __popcll(bal);
                if (cw) {
                    int ldr = __ffsll((long long)bal) - 1;
                    int bw = 0;
                    if (lane == ldr) bw = atomicAdd(&sK, cw);
                    bw = __shfl(bw, ldr);
                    if (f) {
                        int p = bw + __popcll(bal & ((1ull << lane) - 1ull));
                        kk[p] = key; ks[p] = s;
                    }
                }
            }
        }
        __syncthreads();
        int K = sK;
        int T = DETS - emitted;
        if (T > K) T = K;
        if (emitted < DETS && K > 0) {
            ull P = 0;
            if (K > T) {
                int rem = T;
                for (int pass = 7; pass >= 0; --pass) {
                    int sh = pass * 8;
                    *reinterpret_cast<uint4*>(&histw[tid * 4]) = make_uint4(0, 0, 0, 0);
                    __syncthreads();
                    ull pmask = (pass == 7) ? 0ull : (~0ull << (sh + 8));
                    unsigned* hw = &histw[warp << 8];
                    for (int i = tid; i < K; i += 1024) {
                        ull k2 = kk[i];
                        if ((k2 & pmask) == P)
                            atomicAdd(&hw[(unsigned)(k2 >> sh) & 255u], 1u);
                    }
                    __syncthreads();
                    unsigned x = 0, pfx = 0;
                    if (tid < 256) {
                        int d = 255 - tid;
                        #pragma unroll
                        for (int w = 0; w < 16; ++w) x += histw[(w << 8) + d];
                        pfx = x;
                        #pragma unroll
                        for (int o = 1; o < 64; o <<= 1) {
                            unsigned v = __shfl_up(pfx, o);
                            if (lane >= o) pfx += v;
                        }
                        if (lane == 63) wtot4[tid >> 6] = pfx;
                    }
                    __syncthreads();
                    if (tid < 256) {
                        int d = 255 - tid;
                        int ws = tid >> 6;
                        unsigned add = 0;
                        if (ws > 0) add += wtot4[0];
                        if (ws > 1) add += wtot4[1];
                        if (ws > 2) add += wtot4[2];
                        unsigned pi   = pfx + add;
                        unsigned excl = pi - x;
                        if (x && excl < (unsigned)rem && pi >= (unsigned)rem) {
                            sP = P | ((ull)(unsigned)d << sh);
                            int nr = rem - (int)excl;
                            sRem = nr;
                            sDone = ((int)x == nr) ? 1 : 0;
                        }
                    }
                    __syncthreads();
                    P = sP; rem = sRem;
                    if (sDone) break;
                }
            }
            if (tid == 0) sFC = 0;
            __syncthreads();
            for (int i = tid; i < K; i += 1024) {
                ull k2 = kk[i];
                bool sel = (k2 >= P);
                ull bal = __ballot(sel);
                int cw = __popcll(bal);
                if (cw) {
                    int ldr = __ffsll((long long)bal) - 1;
                    int bw = 0;
                    if (lane == ldr) bw = atomicAdd(&sFC, cw);
                    bw = __shfl(bw, ldr);
                    if (sel) {
                        int p2 = bw + __popcll(bal & ((1ull << lane) - 1ull));
                        if (p2 < T) { fkey[p2] = k2; fslot[p2] = ks[i]; }
                    }
                }
            }
            __syncthreads();
            int FC = sFC; if (FC > T) FC = T;
            for (int i = FC + tid; i < 128; i += 1024) { fkey[i] = 0; fslot[i] = -1; }
            __syncthreads();
            if (warp == 0) {
                int base2 = lane * 2;
                ull a = fkey[base2], bb = fkey[base2 + 1];
                int pa = fslot[base2], pb = fslot[base2 + 1];
                #pragma unroll
                for (int k = 2; k <= 128; k <<= 1)
                    wl_pair(a, bb, pa, pb, lane, base2, k,
                            (k >> 1) < 64 ? (k >> 1) : 64);
                #pragma unroll
                for (int e = 0; e < 2; ++e) {
                    int rnk = base2 + e;
                    ull kv = e ? bb : a;
                    int sl = e ? pb : pa;
                    (void)kv;
                    if (rnk < T && sl >= 0) {
                        int r2 = emitted + rnk;
                        int g = b * TOPK + sl;
                        float4 bx = cbox[g];
                        *reinterpret_cast<float4*>(out + ((size_t)b * DETS + r2) * 4) = bx;
                        out[NIMG * DETS * 4 + b * DETS + r2] =
                            (seg == 0) ? cscore[g] : -1.0f;
                        out[NIMG * DETS * 5 + b * DETS + r2] = (float)clabel[g];
                    }
                }
            }
            emitted += T;
        }
        __syncthreads();
    }
}

// ---------------- launch ----------------
extern "C" void kernel_launch(void* const* d_in, const int* in_sizes, int n_in,
                              void* d_out, int out_size, void* d_ws, size_t ws_size,
                              hipStream_t stream) {
    const float* logits = (const float*)d_in[0];   // [16000, 91]
    const float* reg    = (const float*)d_in[1];   // [16000, 364]
    const float* props  = (const float*)d_in[2];   // [8, 2000, 4]
    float* out = (float*)d_out;                    // boxes(3200) | scores(800) | labels(800)
    char* ws = (char*)d_ws;

    int* cntv   = (int*)(ws + OFF_CNT);
    ull* vbm2   = (ull*)(ws + OFF_VBM);
    ull* ck     = (ull*)(ws + OFF_CK);
    float4* cbox   = (float4*)(ws + OFF_CBOX);
    float*  cscor  = (float*)(ws + OFF_CSCOR);
    int*    clab   = (int*)(ws + OFF_CLAB);
    float4* clsbox = (float4*)(ws + OFF_CLSBOX);
    float*  clsar  = (float*)(ws + OFF_CLSAR);
    ull*    clskey = (ull*)(ws + OFF_CLSKEY);
    int*    keepf  = (int*)(ws + OFF_KEEPF);
    int*    clscnt = (int*)(ws + OFF_CLSCNT);
    int*    clsoff = (int*)(ws + OFF_CLSOFF);

    hipMemsetAsync(ws, 0, 2048, stream);   // zero the padded counters only
    hipLaunchKernelGGL(kA, dim3(NROW / 16), dim3(1024), 0, stream,
                       logits, reg, props, ck, cntv, vbm2);
    hipLaunchKernelGGL(kB, dim3(NIMG), dim3(1024), 0, stream,
                       ck, cntv, vbm2, reg, props, cbox, cscor, clab,
                       clsbox, clsar, clskey, keepf, clscnt, clsoff);
    hipLaunchKernelGGL(kN, dim3(NIMG * NFG), dim3(64), 0, stream,
                       clsbox, clsar, clskey, clscnt, clsoff, keepf);
    hipLaunchKernelGGL(kE, dim3(NIMG), dim3(1024), 0, stream,
                       keepf, clskey, cbox, cscor, clab, out);
}